// Round 21
// baseline (390.096 us; speedup 1.0000x reference)
//
#include <hip/hip_runtime.h>
#include <hip/hip_bf16.h>
#include <stdint.h>

// ---------------------------------------------------------------------------
// ChebConv with attention + per-(t,k) dropout, MI355X bf16 MFMA implementation
// out[b,t,u,o] = relu( sum_k M[t,k] @ x[b,t] @ Theta[k] )   (associativity)
// mask = threefry2x32 partitionable, key(42), bits = x0^x1   (verified R0)
// B=32 T=12 V=1000(pad 1024) F=O=64 K=3
//
// R21: R20 (K=3072 single GEMM, 64x64 wave tiles, LDS dbuf 1-barrier/chunk,
// XOR swizzle -- 193us @ 35% MfmaUtil, conflicts 0) + two fixes:
// (1) build_yt reverted to R12's 6144-block grid (R20's 768-block version
//     was ~125us; R12's was ~35us).
// (2) gemm depth-2 register prefetch (named P/Q sets): R20 issued chunk c+1
//     loads only ~620cy before the ds_write consumed them (< L2 latency
//     under load ~700-900cy). Depth-2 gives ~1300cy. Barriers unchanged.
// ws: M row-major [36][1024][1024] bf16 (75.5MB) | yt [3][12][NR][1024] bf16
// ---------------------------------------------------------------------------

typedef __attribute__((ext_vector_type(8))) short short8;
typedef __attribute__((ext_vector_type(4))) float f32x4;

__device__ __forceinline__ ushort f2bf(float f) {
  __hip_bfloat16 h = __float2bfloat16(f);
  return *reinterpret_cast<ushort*>(&h);
}

__device__ __forceinline__ short8 cvt8(float4 a, float4 b) {
  short8 r;
  r[0] = (short)f2bf(a.x); r[1] = (short)f2bf(a.y);
  r[2] = (short)f2bf(a.z); r[3] = (short)f2bf(a.w);
  r[4] = (short)f2bf(b.x); r[5] = (short)f2bf(b.y);
  r[6] = (short)f2bf(b.z); r[7] = (short)f2bf(b.w);
  return r;
}

__device__ __forceinline__ void threefry2x32(uint32_t c0, uint32_t c1,
                                             uint32_t& o0, uint32_t& o1) {
  const uint32_t ks0 = 0u;
  const uint32_t ks1 = 42u;
  const uint32_t ks2 = ks0 ^ ks1 ^ 0x1BD11BDAu;
  uint32_t x0 = c0 + ks0;
  uint32_t x1 = c1 + ks1;
#define TFR(r) { x0 += x1; x1 = (x1 << (r)) | (x1 >> (32 - (r))); x1 ^= x0; }
  TFR(13) TFR(15) TFR(26) TFR(6)
  x0 += ks1; x1 += ks2 + 1u;
  TFR(17) TFR(29) TFR(16) TFR(24)
  x0 += ks2; x1 += ks0 + 2u;
  TFR(13) TFR(15) TFR(26) TFR(6)
  x0 += ks0; x1 += ks1 + 3u;
  TFR(17) TFR(29) TFR(16) TFR(24)
  x0 += ks1; x1 += ks2 + 4u;
  TFR(13) TFR(15) TFR(26) TFR(6)
  x0 += ks2; x1 += ks0 + 5u;
#undef TFR
  o0 = x0; o1 = x1;
}

// ---------------------------------------------------------------------------
// Kernel 1: build masked M (bf16) row-major padded [36][1024][1024]
// ---------------------------------------------------------------------------
__global__ void build_m(const float* __restrict__ Att,
                        const float* __restrict__ cheb,
                        ushort* __restrict__ Mws) {
  const uint32_t idx = blockIdx.x * 256u + threadIdx.x;
  const uint32_t vp = idx & 1023u;
  const uint32_t up = (idx >> 10) & 1023u;
  const uint32_t tk = idx >> 20;
  float val = 0.f;
  if ((vp < 1000u) & (up < 1000u)) {
    const uint32_t flat = (tk * 1000u + up) * 1000u + vp;
    uint32_t o0, o1;
    threefry2x32(0u, flat, o0, o1);
    const uint32_t bits = o0 ^ o1;
    const float u = __uint_as_float((bits >> 9) | 0x3f800000u) - 1.0f;
    if (u < 0.4f) {
      val = cheb[(tk % 3u) * 1000000u + up * 1000u + vp] *
            Att[up * 1000u + vp] * 2.5f;
    }
  }
  Mws[idx] = f2bf(val);
}

// ---------------------------------------------------------------------------
// Kernel 2: build_yt (R12's proven 1-vc-per-block version).
// y_k[b,t] = x[b,t] @ Theta_k, stored transposed row-major:
// yt[k][t][nrow=(b-bq0)*64+o][v pad 1024] bf16.
// 192 thr (3 waves), wave w <-> k=w; block = (vc, t, bb).
// ---------------------------------------------------------------------------
#define MFMA(a, b, c) __builtin_amdgcn_mfma_f32_16x16x32_bf16((a), (b), (c), 0, 0, 0)

__global__ __launch_bounds__(192, 1)
void build_yt(const float* __restrict__ x, const float* __restrict__ Theta,
              ushort* __restrict__ yt, int NR, int bq0) {
  __shared__ __align__(16) ushort sm[27648];  // sTh [0,13824) | sY [13824,..)
  const int tid = threadIdx.x, lane = tid & 63, w = tid >> 6;
  const int quad = lane >> 4, l15 = lane & 15;
  const int vc = blockIdx.x, t = blockIdx.y, bb = blockIdx.z;
  const int b = bq0 + bb;
  const int v0 = vc * 64;

  // stage ThetaT: sTh[k][o][f] = Theta[k][f][o]
  for (int e = tid; e < 12288; e += 192) {
    const int k = e >> 12, rem = e & 4095, f = rem >> 6, o = rem & 63;
    sm[k * 4608 + o * 72 + f] = f2bf(Theta[e]);
  }
  __syncthreads();

  f32x4 pacc[4][4];
#pragma unroll
  for (int i = 0; i < 4; ++i)
#pragma unroll
    for (int j = 0; j < 4; ++j) pacc[i][j] = f32x4{0.f, 0.f, 0.f, 0.f};

  const ushort* sTh = sm + w * 4608;      // wave-private k slab
  const float* xb = x + (((size_t)b * 12 + t) * 1000) * 64;

#pragma unroll
  for (int ks = 0; ks < 2; ++ks) {
    short8 av[4], bv[4];
#pragma unroll
    for (int mi = 0; mi < 4; ++mi)
      av[mi] = *(const short8*)&sTh[(mi * 16 + l15) * 72 + ks * 32 + quad * 8];
#pragma unroll
    for (int ni = 0; ni < 4; ++ni) {
      const int v = v0 + ni * 16 + l15;
      float4 c0 = make_float4(0.f, 0.f, 0.f, 0.f);
      float4 c1 = make_float4(0.f, 0.f, 0.f, 0.f);
      if (v < 1000) {
        const float* row = xb + (size_t)v * 64 + ks * 32 + quad * 8;
        c0 = *(const float4*)row;
        c1 = *(const float4*)(row + 4);
      }
      bv[ni] = cvt8(c0, c1);
    }
#pragma unroll
    for (int mi = 0; mi < 4; ++mi)
#pragma unroll
      for (int ni = 0; ni < 4; ++ni)
        pacc[mi][ni] = MFMA(av[mi], bv[ni], pacc[mi][ni]);
  }

  // wave-local transpose: overlay own region
  ushort* sY = sm + 13824 + w * 4608;
#pragma unroll
  for (int mi = 0; mi < 4; ++mi)
#pragma unroll
    for (int ni = 0; ni < 4; ++ni)
#pragma unroll
      for (int r = 0; r < 4; ++r)
        sY[(mi * 16 + quad * 4 + r) * 72 + ni * 16 + l15] = f2bf(pacc[mi][ni][r]);

  const int seg = lane & 7;
#pragma unroll
  for (int p = 0; p < 8; ++p) {
    const int o = p * 8 + (lane >> 3);
    const uint4 val = *(const uint4*)&sY[o * 72 + seg * 8];
    *(uint4*)(yt + (((size_t)(w * 12 + t) * (size_t)NR + (size_t)bb * 64 + o) << 10)
                 + v0 + seg * 8) = val;
  }
}

// ---------------------------------------------------------------------------
// Kernel 3: K=3072 GEMM.  256 thr (4 waves, 2x2), block 128u x 128n per t,
// wave tile 64x64.  48 chunks of K=64.  LDS dbuf 2x32KB -> 2 blocks/CU.
// DEPTH-2 register prefetch (P/Q named sets): loads get ~1300cy to land.
//   even: LOADQ(c+2); BURST(buf0); WRITEP(buf1)[chunk c+1]; sync
//   odd:  LOADP(c+3); BURST(buf1); WRITEQ(buf0)[chunk c+2]; sync
// Content XOR-swizzle (verified, 0 conflicts): LDS[r][c16B] = G[r][c^(r&7)].
// Epilogue: relu + f32 store straight from pacc.
// Grid XCD-bijective, ut-fastest (8 ut-blocks share B panel in L2).
// ---------------------------------------------------------------------------
#define LOADCH(R0, R1, R2, R3, R4, R5, R6, R7, C)                             \
  do {                                                                        \
    const size_t koA_ = ((size_t)((C) >> 4) << 20) + (size_t)(((C) & 15) * 64); \
    const size_t koB_ = (size_t)((C) >> 4) * ytk + (size_t)(((C) & 15) * 64); \
    R0 = *(const uint4*)(Mws + aS0 + koA_);                                   \
    R1 = *(const uint4*)(Mws + aS1 + koA_);                                   \
    R2 = *(const uint4*)(Mws + aS2 + koA_);                                   \
    R3 = *(const uint4*)(Mws + aS3 + koA_);                                   \
    R4 = *(const uint4*)(yt + bS0 + koB_);                                    \
    R5 = *(const uint4*)(yt + bS1 + koB_);                                    \
    R6 = *(const uint4*)(yt + bS2 + koB_);                                    \
    R7 = *(const uint4*)(yt + bS3 + koB_);                                    \
  } while (0)

#define WRITECH(R0, R1, R2, R3, R4, R5, R6, R7, BP)                           \
  do {                                                                        \
    *(uint4*)&(BP)[(tid) * 8]               = R0;                             \
    *(uint4*)&(BP)[(256 + tid) * 8]         = R1;                             \
    *(uint4*)&(BP)[(512 + tid) * 8]         = R2;                             \
    *(uint4*)&(BP)[(768 + tid) * 8]         = R3;                             \
    *(uint4*)&(BP)[8192 + (tid) * 8]        = R4;                             \
    *(uint4*)&(BP)[8192 + (256 + tid) * 8]  = R5;                             \
    *(uint4*)&(BP)[8192 + (512 + tid) * 8]  = R6;                             \
    *(uint4*)&(BP)[8192 + (768 + tid) * 8]  = R7;                             \
  } while (0)

#define BURST(BP)                                                             \
  do {                                                                        \
    _Pragma("unroll")                                                         \
    for (int ks = 0; ks < 2; ++ks) {                                          \
      const int cs_ = (((ks * 4 + quad) ^ rsw)) << 3;                         \
      short8 av[4], bv[4];                                                    \
      _Pragma("unroll")                                                       \
      for (int mi = 0; mi < 4; ++mi)                                          \
        av[mi] = *(const short8*)&(BP)[(wr * 64 + mi * 16 + l15) * 64 + cs_]; \
      _Pragma("unroll")                                                       \
      for (int ni = 0; ni < 4; ++ni)                                          \
        bv[ni] = *(const short8*)&(BP)[8192 +                                 \
                     (wc * 64 + ni * 16 + l15) * 64 + cs_];                   \
      _Pragma("unroll")                                                       \
      for (int mi = 0; mi < 4; ++mi)                                          \
        _Pragma("unroll")                                                     \
        for (int ni = 0; ni < 4; ++ni)                                        \
          pacc[mi][ni] = MFMA(av[mi], bv[ni], pacc[mi][ni]);                  \
    }                                                                         \
  } while (0)

__global__ __launch_bounds__(256, 2)
void gemm_main(const ushort* __restrict__ Mws, const ushort* __restrict__ yt,
               float* __restrict__ out, int NR, int bq0, int ntcnt) {
  __shared__ __align__(16) ushort smem[32768];  // 64KB: buf0 | buf1
  const int tid = threadIdx.x, lane = tid & 63, w = tid >> 6;
  const int wr = w >> 1, wc = w & 1;            // 2x2 wave grid, tile 64x64
  const int quad = lane >> 4, l15 = lane & 15, rsw = l15 & 7;

  ushort* buf0 = smem;
  ushort* buf1 = smem + 16384;

  // XCD-bijective decode (gridDim.x % 8 == 0), ut-fastest per XCD chunk
  const int nb = (int)gridDim.x;
  const int swz = ((int)blockIdx.x & 7) * (nb >> 3) + ((int)blockIdx.x >> 3);
  const int ut = swz & 7;
  const int g = swz >> 3;
  const int nt = g % ntcnt;
  const int t = g / ntcnt;
  const int u0 = ut * 128, n0 = nt * 128;

  // staging geometry (content XOR pre-swizzle on 16B chunks, verified)
  const size_t mbase = (size_t)(t * 3) << 20;
  const size_t ytk = (size_t)12 * (size_t)NR * 1024;
  const int r0 = tid >> 3,         c0s = (tid & 7) ^ (r0 & 7);
  const int r1 = (256 + tid) >> 3, c1s = (tid & 7) ^ (r1 & 7);
  const int r2 = (512 + tid) >> 3, c2s = (tid & 7) ^ (r2 & 7);
  const int r3 = (768 + tid) >> 3, c3s = (tid & 7) ^ (r3 & 7);
  const size_t aS0 = mbase + ((size_t)(u0 + r0) << 10) + c0s * 8;
  const size_t aS1 = mbase + ((size_t)(u0 + r1) << 10) + c1s * 8;
  const size_t aS2 = mbase + ((size_t)(u0 + r2) << 10) + c2s * 8;
  const size_t aS3 = mbase + ((size_t)(u0 + r3) << 10) + c3s * 8;
  const size_t bbase = ((size_t)t * (size_t)NR + n0) << 10;
  const size_t bS0 = bbase + ((size_t)r0 << 10) + c0s * 8;
  const size_t bS1 = bbase + ((size_t)r1 << 10) + c1s * 8;
  const size_t bS2 = bbase + ((size_t)r2 << 10) + c2s * 8;
  const size_t bS3 = bbase + ((size_t)r3 << 10) + c3s * 8;

  f32x4 pacc[4][4];
#pragma unroll
  for (int i = 0; i < 4; ++i)
#pragma unroll
    for (int j = 0; j < 4; ++j) pacc[i][j] = f32x4{0.f, 0.f, 0.f, 0.f};

  uint4 q0, q1, q2, q3, q4, q5, q6, q7;   // set P
  uint4 s0, s1, s2, s3, s4, s5, s6, s7;   // set Q

  // prologue: chunk 0 staged; chunk 1 into P
  LOADCH(q0, q1, q2, q3, q4, q5, q6, q7, 0);
  WRITECH(q0, q1, q2, q3, q4, q5, q6, q7, buf0);
  LOADCH(q0, q1, q2, q3, q4, q5, q6, q7, 1);
  __syncthreads();

  // main K loop: 48 chunks, one barrier per chunk, depth-2 reg prefetch
#pragma unroll 1
  for (int it = 0; it < 24; ++it) {
    const int c = it * 2;
    // even chunk: read buf0; issue c+2 -> Q; commit P (c+1) -> buf1
    if (c + 2 < 48) LOADCH(s0, s1, s2, s3, s4, s5, s6, s7, c + 2);
    __builtin_amdgcn_s_setprio(1);
    BURST(buf0);
    __builtin_amdgcn_s_setprio(0);
    WRITECH(q0, q1, q2, q3, q4, q5, q6, q7, buf1);
    __syncthreads();
    // odd chunk: read buf1; issue c+3 -> P; commit Q (c+2) -> buf0
    if (c + 3 < 48) LOADCH(q0, q1, q2, q3, q4, q5, q6, q7, c + 3);
    __builtin_amdgcn_s_setprio(1);
    BURST(buf1);
    __builtin_amdgcn_s_setprio(0);
    if (c + 2 < 48) WRITECH(s0, s1, s2, s3, s4, s5, s6, s7, buf0);
    __syncthreads();
  }

  // epilogue: relu + f32 store
#pragma unroll
  for (int mi = 0; mi < 4; ++mi) {
    const int u_base = u0 + wr * 64 + mi * 16 + quad * 4;
#pragma unroll
    for (int ni = 0; ni < 4; ++ni) {
      const int n = n0 + wc * 64 + ni * 16 + l15;
      const int b = bq0 + (n >> 6), o = n & 63;
      float* op = out + (((size_t)b * 12 + t) * 1000) * 64 + o;
#pragma unroll
      for (int r = 0; r < 4; ++r) {
        const int u = u_base + r;
        if (u < 1000) op[(size_t)u * 64] = fmaxf(pacc[mi][ni][r], 0.f);
      }
    }
  }
}

// ---------------------------------------------------------------------------
extern "C" void kernel_launch(void* const* d_in, const int* in_sizes, int n_in,
                              void* d_out, int out_size, void* d_ws, size_t ws_size,
                              hipStream_t stream) {
  const float* x     = (const float*)d_in[0];
  const float* Att   = (const float*)d_in[1];
  const float* cheb  = (const float*)d_in[2];
  const float* Theta = (const float*)d_in[3];
  float* out = (float*)d_out;

  ushort* Mws = (ushort*)d_ws;           // 75.5 MB row-major padded M
  ushort* yt  = Mws + 37748736ull;       // yt region

  build_m<<<147456, 256, 0, stream>>>(Att, cheb, Mws);

  if (ws_size >= 226492416ull) {
    // full path: yt [3][12][2048][1024] bf16 (151MB)
    build_yt<<<dim3(16, 12, 32), 192, 0, stream>>>(x, Theta, yt, 2048, 0);
    gemm_main<<<1536, 256, 0, stream>>>(Mws, yt, out, 2048, 0, 16);
  } else {
    // quarter path: 4 passes of 8 batches; yt [3][12][512][1024] (37.7MB)
    for (int qq = 0; qq < 4; ++qq) {
      build_yt<<<dim3(16, 12, 8), 192, 0, stream>>>(x, Theta, yt, 512, qq * 8);
      gemm_main<<<384, 256, 0, stream>>>(Mws, yt, out, 512, qq * 8, 4);
    }
  }
}

// Round 22
// 271.693 us; speedup vs baseline: 1.4358x; 1.4358x over previous
//
#include <hip/hip_runtime.h>
#include <hip/hip_bf16.h>
#include <stdint.h>

// ---------------------------------------------------------------------------
// ChebConv with attention + per-(t,k) dropout, MI355X bf16 MFMA implementation
// out[b,t,u,o] = relu( sum_k M[t,k] @ (x[b,t] @ Theta[k]) )
// mask = threefry2x32 partitionable, key(42), bits = x0^x1   (verified R0)
// B=32 T=12 V=1000(pad 1024) F=O=64 K=3
// ws: Mf frag-order [36<<20] bf16 (75.5MB) | xt row-major [12][2048][1024]
//
// R22: R19 (session-best 272us: fused prep + hybrid cheb_main -- A direct
// from fragment-order Mf, B via LDS dbuf 1-barrier/chunk, XOR swizzle)
// + nontemporal out-stores (96MB streamed once; keep L2/L3 for M/xt reuse).
// R8-R21 establish the 2-phase schedule ceiling at MfmaUtil ~35% across ten
// structural variants (matches guide m233/m97-class); the 8-phase+gl_lds
// escape (m201) failed its prerequisite in R2 and needs two risky rewrites.
// ---------------------------------------------------------------------------

typedef __attribute__((ext_vector_type(8))) short short8;
typedef __attribute__((ext_vector_type(4))) float f32x4;

__device__ __forceinline__ ushort f2bf(float f) {
  __hip_bfloat16 h = __float2bfloat16(f);
  return *reinterpret_cast<ushort*>(&h);
}

__device__ __forceinline__ void threefry2x32(uint32_t c0, uint32_t c1,
                                             uint32_t& o0, uint32_t& o1) {
  const uint32_t ks0 = 0u;
  const uint32_t ks1 = 42u;
  const uint32_t ks2 = ks0 ^ ks1 ^ 0x1BD11BDAu;
  uint32_t x0 = c0 + ks0;
  uint32_t x1 = c1 + ks1;
#define TFR(r) { x0 += x1; x1 = (x1 << (r)) | (x1 >> (32 - (r))); x1 ^= x0; }
  TFR(13) TFR(15) TFR(26) TFR(6)
  x0 += ks1; x1 += ks2 + 1u;
  TFR(17) TFR(29) TFR(16) TFR(24)
  x0 += ks2; x1 += ks0 + 2u;
  TFR(13) TFR(15) TFR(26) TFR(6)
  x0 += ks0; x1 += ks1 + 3u;
  TFR(17) TFR(29) TFR(16) TFR(24)
  x0 += ks1; x1 += ks2 + 4u;
  TFR(13) TFR(15) TFR(26) TFR(6)
  x0 += ks2; x1 += ks0 + 5u;
#undef TFR
  o0 = x0; o1 = x1;
}

// ---------------------------------------------------------------------------
// Kernel 1 (fused prep): blocks [0,6144) = transpose_x (HBM-bound),
// [6144,153600) = build_m in FRAGMENT order (VALU-bound) -- pipes overlap.
// Frag order (R11/R16-verified): elem = (((tk*64+u16)*16+vc)*2+ks)*512
//   + lane*8 + j;  u = u16*16+(lane&15), v = vc*64+ks*32+(lane>>4)*8+j.
// ---------------------------------------------------------------------------
__global__ void prep(const float* __restrict__ x,
                     const float* __restrict__ Att,
                     const float* __restrict__ cheb,
                     ushort* __restrict__ Mf,
                     ushort* __restrict__ xtw) {
  __shared__ float lt[64][65];
  const int bid = blockIdx.x;
  const int tid = threadIdx.x;

  if (bid >= 6144) {
    // ---- build_m role: masked M in MFMA-fragment order ----
    const uint32_t idx = (uint32_t)(bid - 6144) * 256u + tid;
    const uint32_t j = idx & 7u;
    const uint32_t lane = (idx >> 3) & 63u;
    const uint32_t ks = (idx >> 9) & 1u;
    const uint32_t c = (idx >> 10) & 15u;
    const uint32_t u16 = (idx >> 14) & 63u;
    const uint32_t tk = idx >> 20;
    const uint32_t up = u16 * 16u + (lane & 15u);
    const uint32_t vp = c * 64u + ks * 32u + (lane >> 4) * 8u + j;
    float val = 0.f;
    if ((vp < 1000u) & (up < 1000u)) {
      const uint32_t flat = (tk * 1000u + up) * 1000u + vp;
      uint32_t o0, o1;
      threefry2x32(0u, flat, o0, o1);
      const uint32_t bits = o0 ^ o1;
      const float u = __uint_as_float((bits >> 9) | 0x3f800000u) - 1.0f;
      if (u < 0.4f) {
        val = cheb[(tk % 3u) * 1000000u + up * 1000u + vp] *
              Att[up * 1000u + vp] * 2.5f;
      }
    }
    Mf[idx] = f2bf(val);
    return;
  }

  // ---- transpose role: xt[t][n=b*64+f][v pad 1024] <- x[b][t][v][f] ----
  const int r = bid;
  const int vc = r & 15, t = (r >> 4) % 12, b = r / 192;
  const int v0 = vc * 64;
#pragma unroll
  for (int i = 0; i < 4; ++i) {
    const int c = i * 256 + tid;
    const int vi = c >> 4, f4 = c & 15;
    float4 q = make_float4(0.f, 0.f, 0.f, 0.f);
    if (v0 + vi < 1000)
      q = *(const float4*)(x + ((((size_t)b * 12 + t) * 1000 + v0 + vi) << 6) + f4 * 4);
    lt[f4 * 4 + 0][vi] = q.x;
    lt[f4 * 4 + 1][vi] = q.y;
    lt[f4 * 4 + 2][vi] = q.z;
    lt[f4 * 4 + 3][vi] = q.w;
  }
  __syncthreads();
  const int f = tid >> 2, g = tid & 3;
  alignas(16) ushort tmp[16];
#pragma unroll
  for (int j = 0; j < 16; ++j) tmp[j] = f2bf(lt[f][g * 16 + j]);
  const size_t base = ((size_t)(t * 2048 + b * 64 + f)) << 10;
  *(uint4*)(xtw + base + v0 + g * 16)     = *(const uint4*)&tmp[0];
  *(uint4*)(xtw + base + v0 + g * 16 + 8) = *(const uint4*)&tmp[8];
}

// ---------------------------------------------------------------------------
// Kernel 2: main fused GEMM, hybrid operand paths (R19-verified).
// 256 thr (4 waves, 2x2), block 64u x 128n per t, wave tile 32u x 64n.
// Per 64-chunk: A = 12 frag loads direct from Mf (coalesced 1KB, L2-hot);
// B = LDS dbuf (2x16KB, one barrier/chunk, issue-early reg prefetch,
// XOR content swizzle). 48 MFMA into pacc[3] (AGPR).
// Stage 2 (k unrolled): pacc[k] -> sP -> oacc += P @ ThetaT[k].
// Epilogue: relu + NONTEMPORAL f32 store (out never re-read).
// Grid 3072 1D, XCD-bijective, ut-fastest (A panels L2-hot per XCD).
// ---------------------------------------------------------------------------
#define LDT 72
#define MFMA(a, b, c) __builtin_amdgcn_mfma_f32_16x16x32_bf16((a), (b), (c), 0, 0, 0)

#define LOADB(VC)                                                             \
  do {                                                                        \
    const size_t co_ = (size_t)(VC) * 64;                                     \
    p6 = *(const uint4*)(xt + bS0 + co_);                                     \
    p7 = *(const uint4*)(xt + bS1 + co_);                                     \
    p8 = *(const uint4*)(xt + bS2 + co_);                                     \
    p9 = *(const uint4*)(xt + bS3 + co_);                                     \
  } while (0)

#define WRITEB(BP)                                                            \
  do {                                                                        \
    *(uint4*)&(BP)[(tid) * 8]        = p6;                                    \
    *(uint4*)&(BP)[(256 + tid) * 8]  = p7;                                    \
    *(uint4*)&(BP)[(512 + tid) * 8]  = p8;                                    \
    *(uint4*)&(BP)[(768 + tid) * 8]  = p9;                                    \
  } while (0)

#define LOADA(VC)                                                             \
  do {                                                                        \
    const size_t co_ = (size_t)(VC) << 10;                                    \
    _Pragma("unroll")                                                         \
    for (int k = 0; k < 3; ++k)                                               \
      _Pragma("unroll")                                                       \
      for (int mi = 0; mi < 2; ++mi)                                          \
        _Pragma("unroll")                                                     \
        for (int ks = 0; ks < 2; ++ks)                                        \
          a[k][mi][ks] = *(const short8*)(Mf + fA[k][mi] + co_ +              \
                                          ((size_t)ks << 9));                 \
  } while (0)

#define BURST(BP)                                                             \
  do {                                                                        \
    _Pragma("unroll")                                                         \
    for (int ks = 0; ks < 2; ++ks) {                                          \
      const int cs_ = (((ks * 4 + quad) ^ rsw)) << 3;                         \
      short8 bv[4];                                                           \
      _Pragma("unroll")                                                       \
      for (int ni = 0; ni < 4; ++ni)                                          \
        bv[ni] = *(const short8*)&(BP)[(wn * 64 + ni * 16 + l15) * 64 + cs_]; \
      _Pragma("unroll")                                                       \
      for (int k = 0; k < 3; ++k)                                             \
        _Pragma("unroll")                                                     \
        for (int mi = 0; mi < 2; ++mi)                                        \
          _Pragma("unroll")                                                   \
          for (int ni = 0; ni < 4; ++ni)                                      \
            pacc[k][mi][ni] = MFMA(a[k][mi][ks], bv[ni], pacc[k][mi][ni]);    \
    }                                                                         \
  } while (0)

__global__ __launch_bounds__(256, 2)
void cheb_main(const ushort* __restrict__ Mf, const ushort* __restrict__ xt,
               const float* __restrict__ Theta, float* __restrict__ out) {
  __shared__ __align__(16) ushort smem[16384];  // 32KB: B buf0 | buf1
  const int tid = threadIdx.x;
  const int lane = tid & 63;
  const int w = tid >> 6;              // wave 0..3
  const int wu = w >> 1, wn = w & 1;   // wave tile: u = wu*32, n = wn*64
  const int quad = lane >> 4, l15 = lane & 15;
  const int rsw = l15 & 7;

  ushort* buf0 = smem;
  ushort* buf1 = smem + 8192;

  // XCD-bijective decode (3072 % 8 == 0), ut-fastest within each XCD chunk
  const int bid = blockIdx.x;
  const int swz = (bid & 7) * 384 + (bid >> 3);
  const int ut = swz & 15;
  const int g = swz >> 4;              // 0..191
  const int nt = g & 15;
  const int t = g >> 4;                // 0..11
  const int u0 = ut * 64, n0 = nt * 128;

  // A fragment bases (frag-order Mf): u16 = ut*4 + wu*2 + mi
  size_t fA[3][2];
#pragma unroll
  for (int k = 0; k < 3; ++k)
#pragma unroll
    for (int mi = 0; mi < 2; ++mi)
      fA[k][mi] = (((size_t)((t * 3 + k) * 64 + ut * 4 + wu * 2 + mi)) << 14)
                  + (size_t)lane * 8;

  // B staging sources (xt row-major, XOR content pre-swizzle) -- verified
  const size_t xrow0 = (size_t)(t * 2048 + n0);
  const int rB0 = tid >> 3,         cB0 = (tid & 7) ^ (rB0 & 7);
  const int rB1 = (256 + tid) >> 3, cB1 = (tid & 7) ^ (rB1 & 7);
  const int rB2 = (512 + tid) >> 3, cB2 = (tid & 7) ^ (rB2 & 7);
  const int rB3 = (768 + tid) >> 3, cB3 = (tid & 7) ^ (rB3 & 7);
  const size_t bS0 = ((xrow0 + rB0) << 10) + cB0 * 8;
  const size_t bS1 = ((xrow0 + rB1) << 10) + cB1 * 8;
  const size_t bS2 = ((xrow0 + rB2) << 10) + cB2 * 8;
  const size_t bS3 = ((xrow0 + rB3) << 10) + cB3 * 8;

  f32x4 pacc[3][2][4];
#pragma unroll
  for (int k = 0; k < 3; ++k)
#pragma unroll
    for (int i = 0; i < 2; ++i)
#pragma unroll
      for (int j = 0; j < 4; ++j) pacc[k][i][j] = f32x4{0.f, 0.f, 0.f, 0.f};

  short8 a[3][2][2];
  uint4 p6, p7, p8, p9;

  // prologue: B chunk 0 -> buf0
  LOADB(0);
  WRITEB(buf0);
  __syncthreads();

  // main K loop: 16 chunks, unrolled x2 for static buffer pointers;
  // one barrier per chunk (write targets buffer read last iteration)
#pragma unroll 1
  for (int it = 0; it < 8; ++it) {
    const int vc = it * 2;
    // even chunk: read buf0; prefetch B(vc+1) regs; A(vc) direct
    if (vc < 15) LOADB(vc + 1);
    LOADA(vc);
    __builtin_amdgcn_s_setprio(1);
    BURST(buf0);
    __builtin_amdgcn_s_setprio(0);
    if (vc < 15) WRITEB(buf1);
    __syncthreads();
    // odd chunk: read buf1; prefetch B(vc+2); A(vc+1)
    if (vc + 1 < 15) LOADB(vc + 2);
    LOADA(vc + 1);
    __builtin_amdgcn_s_setprio(1);
    BURST(buf1);
    __builtin_amdgcn_s_setprio(0);
    if (vc + 1 < 15) WRITEB(buf0);
    __syncthreads();
  }

  // ---- stage 2: oacc += P_k @ ThetaT[k], k fully unrolled ----
  ushort* sP  = smem + w * 2304;       // 32 x 72, wave-local
  ushort* sTh = smem + 9216;           // 64 x 72  (9216+4608 = 13824 <= 16384)
  f32x4 oacc[2][4];
#pragma unroll
  for (int i = 0; i < 2; ++i)
#pragma unroll
    for (int j = 0; j < 4; ++j) oacc[i][j] = f32x4{0.f, 0.f, 0.f, 0.f};

#pragma unroll
  for (int k = 0; k < 3; ++k) {
    __syncthreads();  // prev readers done
#pragma unroll
    for (int mi = 0; mi < 2; ++mi)
#pragma unroll
      for (int ni = 0; ni < 4; ++ni)
#pragma unroll
        for (int r = 0; r < 4; ++r)
          sP[(mi * 16 + quad * 4 + r) * LDT + ni * 16 + l15] = f2bf(pacc[k][mi][ni][r]);
    for (int e = tid; e < 4096; e += 256) {
      const int f = e >> 6, o = e & 63;
      sTh[o * LDT + f] = f2bf(Theta[k * 4096 + e]);
    }
    __syncthreads();
#pragma unroll
    for (int ks = 0; ks < 2; ++ks) {
      short8 a2[2], b2[4];
#pragma unroll
      for (int mi = 0; mi < 2; ++mi)
        a2[mi] = *(const short8*)&sP[(mi * 16 + l15) * LDT + ks * 32 + quad * 8];
#pragma unroll
      for (int ni = 0; ni < 4; ++ni)
        b2[ni] = *(const short8*)&sTh[(ni * 16 + l15) * LDT + ks * 32 + quad * 8];
#pragma unroll
      for (int mi = 0; mi < 2; ++mi)
#pragma unroll
        for (int ni = 0; ni < 4; ++ni)
          oacc[mi][ni] = MFMA(a2[mi], b2[ni], oacc[mi][ni]);
    }
  }

  // ---- epilogue: relu + nontemporal f32 store (out never re-read) ----
#pragma unroll
  for (int mi = 0; mi < 2; ++mi) {
    const int u_base = u0 + wu * 32 + mi * 16 + quad * 4;
#pragma unroll
    for (int ni = 0; ni < 4; ++ni) {
      const int n = n0 + wn * 64 + ni * 16 + l15;
      const int b = n >> 6, oo = n & 63;
      float* op = out + (((size_t)b * 12 + t) * 1000) * 64 + oo;
#pragma unroll
      for (int r = 0; r < 4; ++r) {
        const int u = u_base + r;
        if (u < 1000)
          __builtin_nontemporal_store(fmaxf(oacc[mi][ni][r], 0.f),
                                      op + (size_t)u * 64);
      }
    }
  }
}

// ---------------------------------------------------------------------------
extern "C" void kernel_launch(void* const* d_in, const int* in_sizes, int n_in,
                              void* d_out, int out_size, void* d_ws, size_t ws_size,
                              hipStream_t stream) {
  const float* x     = (const float*)d_in[0];
  const float* Att   = (const float*)d_in[1];
  const float* cheb  = (const float*)d_in[2];
  const float* Theta = (const float*)d_in[3];
  float* out = (float*)d_out;

  ushort* Mf  = (ushort*)d_ws;                 // 36*1024*1024 bf16, frag order
  ushort* xtw = Mf + 37748736ull;              // 12*2048*1024 bf16 row-major
  // requires ws_size >= 125,829,120 bytes (proven budget)

  prep<<<153600, 256, 0, stream>>>(x, Att, cheb, Mf, xtw);
  cheb_main<<<3072, 256, 0, stream>>>(Mf, xtw, Theta, out);
}